// Round 1
// baseline (194.193 us; speedup 1.0000x reference)
//
#include <hip/hip_runtime.h>
#include <math.h>

#define SLEN 8000
#define NBATCH 512
#define DDIM 256

// ---- conv config ----
#define RAD 160
#define TAPS (2 * RAD + 1)      // 321
#define CHUNK 2048
#define CBLK 256
#define TPO 8                   // outputs per thread
#define WIN (CHUNK + 2 * RAD + 16)   // 2384 (16 pad for prefetch overrun)
#define LDSZ (WIN + WIN / 8)         // 2682 floats, swizzled phi(i)=i+(i>>3)

// output element offsets (flat concat in reference return order)
#define O0  0            // dv_out sliced  512*7700
#define O1  3942400      // dv_t           512*8000
#define O2  8038400      // dv2_t          512*8000
#define O3  12134400     // a              512
#define O4  12134912     // k*1000         512
#define O5  12135424     // epsilon        512
#define O6  12135936     // gamma          512
#define O7  12136448     // t_             512*8000
#define O8  16232448     // dv_l           512*8001
#define O9  20328960     // dv_r           512*8001
#define O10 24425472     // t_out          512*8000

struct WTable { float w[TAPS]; };

// ---------------- params: k,a,eps,gamma = clip(relu(b@w.T + bias), lo, hi) ----
__global__ __launch_bounds__(256) void pc_params_kernel(
    const float* __restrict__ b,
    const float* __restrict__ kw, const float* __restrict__ kb,
    const float* __restrict__ aw, const float* __restrict__ ab,
    const float* __restrict__ ew, const float* __restrict__ eb,
    const float* __restrict__ gw, const float* __restrict__ gb,
    float* __restrict__ out3, float* __restrict__ out4,
    float* __restrict__ out5, float* __restrict__ out6,
    float* __restrict__ wsp)
{
    __shared__ float4 red[256];
    const int row = blockIdx.x;
    const int d = threadIdx.x;
    const float bv = b[row * DDIM + d];
    red[d] = make_float4(bv * kw[d], bv * aw[d], bv * ew[d], bv * gw[d]);
    __syncthreads();
    for (int s2 = 128; s2 > 0; s2 >>= 1) {
        if (d < s2) {
            float4 o = red[d + s2];
            red[d].x += o.x; red[d].y += o.y; red[d].z += o.z; red[d].w += o.w;
        }
        __syncthreads();
    }
    if (d == 0) {
        float4 s = red[0];
        float k = fminf(fmaxf(fmaxf(s.x + kb[0], 0.0f), 0.1f),   1.0f);
        float a = fminf(fmaxf(fmaxf(s.y + ab[0], 0.0f), 0.001f), 0.1f);
        float e = fminf(fmaxf(fmaxf(s.z + eb[0], 0.0f), 0.005f), 0.1f);
        float g = fminf(fmaxf(fmaxf(s.w + gb[0], 0.0f), 0.5f),   2.0f);
        out3[row] = a;
        out4[row] = k * 1000.0f;
        out5[row] = e;
        out6[row] = g;
        wsp[row]          = k;
        wsp[512 + row]    = a;
        wsp[1024 + row]   = e;
        wsp[1536 + row]   = g;
    }
}

// ---------------- truncated Gaussian FIR; writes v_s into dv_l/dv_r outputs --
__global__ __launch_bounds__(CBLK) void pc_conv_kernel(
    const float* __restrict__ v,
    float* __restrict__ dvl,   // out8 base: dv_l[row][i+1] = v_s[row][i]
    float* __restrict__ dvr,   // out9 base: dv_r[row][i]   = v_s[row][i]
    WTable wt)
{
    __shared__ float lds[LDSZ];
    const int row = blockIdx.y;
    const int i0 = blockIdx.x * CHUNK;
    const int tid = threadIdx.x;
    const float* vrow = v + row * SLEN;

    // stage window [i0-RAD, i0-RAD+WIN) with zero padding, swizzled
    for (int idx = tid; idx < WIN; idx += CBLK) {
        const int g = i0 - RAD + idx;
        const float val = (g >= 0 && g < SLEN) ? vrow[g] : 0.0f;
        lds[idx + (idx >> 3)] = val;
    }
    __syncthreads();

    const int base = tid * TPO;
    float acc[TPO];
#pragma unroll
    for (int t = 0; t < TPO; ++t) acc[t] = 0.0f;

    // sliding 16-register window: sreg[k] = win[base + jb + k]
    float sreg[16];
    const float* p0 = lds + 9 * tid;   // phi(8*tid + k) = 9*tid + k (k<8)
#pragma unroll
    for (int k = 0; k < 8; ++k) sreg[k] = p0[k];
#pragma unroll
    for (int k = 0; k < 8; ++k) sreg[8 + k] = p0[9 + k];

#pragma unroll 2
    for (int jb = 0; jb < TAPS - 1; jb += 8) {
#pragma unroll
        for (int c = 0; c < 8; ++c) {
            const float wc = wt.w[jb + c];
#pragma unroll
            for (int t = 0; t < TPO; ++t) acc[t] += wc * sreg[c + t];
        }
#pragma unroll
        for (int k = 0; k < 8; ++k) sreg[k] = sreg[k + 8];
        const float* pn = lds + 9 * tid + 9 * ((jb >> 3) + 2);
#pragma unroll
        for (int k = 0; k < 8; ++k) sreg[8 + k] = pn[k];
    }
    { // final tap j = TAPS-1: sreg[t] = win[base + 320 + t]
        const float wc = wt.w[TAPS - 1];
#pragma unroll
        for (int t = 0; t < TPO; ++t) acc[t] += wc * sreg[t];
    }

    const long rb = (long)row * 8001;
#pragma unroll
    for (int t = 0; t < TPO; ++t) {
        const int i = i0 + base + t;
        if (i < SLEN) {
            dvr[rb + i] = acc[t];
            dvl[rb + i + 1] = acc[t];
            if (i == 0) dvl[rb] = 0.0f;
            if (i == SLEN - 1) dvr[rb + SLEN] = 0.0f;
        }
    }
}

// ---------------- pointwise physics + slicing + constants ------------------
__global__ __launch_bounds__(256) void pc_pointwise_kernel(
    const float* __restrict__ dvr,      // out9 region = [v_s, 0] per row
    const float* __restrict__ wsp,
    const float* __restrict__ v_out,
    const int* __restrict__ use_cond,
    float* __restrict__ out0, float* __restrict__ out1,
    float* __restrict__ out2, float* __restrict__ out7,
    float* __restrict__ out10)
{
    const int row = blockIdx.y;
    const int i = blockIdx.x * 256 + threadIdx.x;
    if (i >= SLEN) return;
    const long rb = (long)row * 8001;

    const float vc = dvr[rb + i];
    const float vm = (i > 0) ? dvr[rb + i - 1] : 0.0f;
    const float vp = dvr[rb + i + 1];   // ==0 at i=SLEN-1 (written by conv)

    const float kk = wsp[row];
    const float aa = wsp[512 + row];
    const float ee = wsp[1024 + row];
    const float gg = wsp[1536 + row];

    constexpr float DT = 1.6f / 7999.0f;
    constexpr float C1 = 1.0f / (2.0f * DT);
    constexpr float C2 = 1.0f / (DT * DT);

    const float dv_t = (vp - vm) * C1;
    const float dv2  = (vp + vm - 2.0f * vc) * C2;

    float vn = (vc == 0.0f) ? 0.001f : vc;
    float inv_v = 1.0f / vn;
    if (inv_v != inv_v) inv_v = 0.0f;

    const float term_l1 = vc * kk * dv_t * (1.0f - 2.0f * vc + aa);
    const float term_l2 = inv_v * dv_t * dv_t;
    const float term_lt = 1000.0f * term_l1 + term_l2 - dv2;
    const float term_r1 = vc * (vc - gg * kk * 1000.0f * (1.0f - vc) * (vc - aa));
    const float term_rt = ee * (term_r1 + gg * dv_t);
    float dvo = term_lt - term_rt;

    if (*use_cond) {
        if (v_out[(long)row * SLEN + i] <= 0.0f) dvo = 0.0f;
    }

    const long rs = (long)row * SLEN;
    out1[rs + i] = dv_t;
    out2[rs + i] = dv2;
    out7[rs + i] = 1.6f;
    out10[rs + i] = 1.6f;

    if (i >= 100 && i < 950) {
        out0[(long)row * 7700 + (i - 100)] = logf(dvo * dvo + 1e-5f);
    } else if (i >= 1050 && i < 7900) {
        out0[(long)row * 7700 + 850 + (i - 1050)] = logf(dvo * dvo + 1e-5f);
    }
}

static void build_wtable(WTable* wt) {
    // reference: k = exp(-x^2/(2*30^2)) over x=-3500..3500, normalized by full sum
    double norm = 0.0;
    for (int d = -3500; d <= 3500; ++d)
        norm += exp(-(double)d * (double)d / 1800.0);
    for (int j = 0; j < TAPS; ++j) {
        const int d = j - RAD;
        wt->w[j] = (float)(exp(-(double)d * (double)d / 1800.0) / norm);
    }
}

extern "C" void kernel_launch(void* const* d_in, const int* in_sizes, int n_in,
                              void* d_out, int out_size, void* d_ws, size_t ws_size,
                              hipStream_t stream)
{
    const float* v_out = (const float*)d_in[0];
    const float* b  = (const float*)d_in[1];
    const float* kw = (const float*)d_in[2];
    const float* kb = (const float*)d_in[3];
    const float* aw = (const float*)d_in[4];
    const float* ab = (const float*)d_in[5];
    const float* ew = (const float*)d_in[6];
    const float* eb = (const float*)d_in[7];
    const float* gw = (const float*)d_in[8];
    const float* gb = (const float*)d_in[9];
    const int* use_cond = (const int*)d_in[10];
    float* out = (float*)d_out;
    float* wsp = (float*)d_ws;   // 2048 floats: k,a,eps,gamma per row

    WTable wt;
    build_wtable(&wt);

    pc_params_kernel<<<NBATCH, 256, 0, stream>>>(
        b, kw, kb, aw, ab, ew, eb, gw, gb,
        out + O3, out + O4, out + O5, out + O6, wsp);

    pc_conv_kernel<<<dim3((SLEN + CHUNK - 1) / CHUNK, NBATCH), CBLK, 0, stream>>>(
        v_out, out + O8, out + O9, wt);

    pc_pointwise_kernel<<<dim3((SLEN + 255) / 256, NBATCH), 256, 0, stream>>>(
        out + O9, wsp, v_out, use_cond,
        out + O0, out + O1, out + O2, out + O7, out + O10);
}

// Round 2
// 190.664 us; speedup vs baseline: 1.0185x; 1.0185x over previous
//
#include <hip/hip_runtime.h>
#include <math.h>

#define SLEN 8000
#define NBATCH 512
#define DDIM 256

// ---- fused conv+pointwise config ----
#define RAD 160
#define TAPS 321                 // truncated Gaussian: tail mass ~1e-7
#define CHUNK 2048
#define CBLK 256
#define TPO 8
#define HALO_L 176               // 16 extra left so v_s[i0-1] is computable
#define WIN (HALO_L + CHUNK + RAD + 16)   // 2400
#define LDSZ (WIN + WIN / 8)              // 2700, swizzle phi(x)=x+(x>>3)

// output element offsets (flat concat in reference return order)
#define O0  0            // dv_out sliced  512*7700
#define O1  3942400      // dv_t           512*8000
#define O2  8038400      // dv2_t          512*8000
#define O3  12134400     // a              512
#define O4  12134912     // k*1000        512
#define O5  12135424     // epsilon        512
#define O6  12135936     // gamma          512
#define O7  12136448     // t_             512*8000
#define O8  16232448     // dv_l           512*8001
#define O9  20328960     // dv_r           512*8001
#define O10 24425472     // t_out          512*8000

// unaligned-capable 16B vector (dv_l/dv_r rows are 8001 floats -> 4B aligned)
typedef float f4u __attribute__((vector_size(16), aligned(4)));

// ---------------- params: k,a,eps,gamma = clip(relu(b@w.T + bias), lo, hi) ----
__global__ __launch_bounds__(256) void pc_params_kernel(
    const float* __restrict__ b,
    const float* __restrict__ kw, const float* __restrict__ kb,
    const float* __restrict__ aw, const float* __restrict__ ab,
    const float* __restrict__ ew, const float* __restrict__ eb,
    const float* __restrict__ gw, const float* __restrict__ gb,
    float* __restrict__ out3, float* __restrict__ out4,
    float* __restrict__ out5, float* __restrict__ out6,
    float* __restrict__ wsp)
{
    __shared__ float4 red[256];
    const int row = blockIdx.x;
    const int d = threadIdx.x;
    const float bv = b[row * DDIM + d];
    red[d] = make_float4(bv * kw[d], bv * aw[d], bv * ew[d], bv * gw[d]);
    __syncthreads();
    for (int s2 = 128; s2 > 0; s2 >>= 1) {
        if (d < s2) {
            float4 o = red[d + s2];
            red[d].x += o.x; red[d].y += o.y; red[d].z += o.z; red[d].w += o.w;
        }
        __syncthreads();
    }
    if (d == 0) {
        float4 s = red[0];
        float k = fminf(fmaxf(fmaxf(s.x + kb[0], 0.0f), 0.1f),   1.0f);
        float a = fminf(fmaxf(fmaxf(s.y + ab[0], 0.0f), 0.001f), 0.1f);
        float e = fminf(fmaxf(fmaxf(s.z + eb[0], 0.0f), 0.005f), 0.1f);
        float g = fminf(fmaxf(fmaxf(s.w + gb[0], 0.0f), 0.5f),   2.0f);
        out3[row] = a;
        out4[row] = k * 1000.0f;
        out5[row] = e;
        out6[row] = g;
        wsp[row]          = k;
        wsp[512 + row]    = a;
        wsp[1024 + row]   = e;
        wsp[1536 + row]   = g;
    }
}

// -------- fused: truncated-Gaussian FIR + finite diffs + physics + outputs ---
__global__ __launch_bounds__(CBLK) void pc_fused_kernel(
    const float* __restrict__ v,
    const float* __restrict__ wsp,
    const int* __restrict__ use_cond,
    float* __restrict__ out0, float* __restrict__ out1,
    float* __restrict__ out2, float* __restrict__ out7,
    float* __restrict__ dvl,  float* __restrict__ dvr,
    float* __restrict__ out10)
{
    __shared__ float lds[LDSZ];
    __shared__ __align__(16) float wlds[TAPS + 7];
    __shared__ float eL[CBLK], eR[CBLK];

    const int row = blockIdx.y;
    const int i0 = blockIdx.x * CHUNK;
    const int tid = threadIdx.x;
    const float* vrow = v + (long)row * SLEN;

    // weights into LDS: w[j] = exp(-(j-160)^2/1800) / (sigma*sqrt(2*pi))
    // (truncated-norm == full-norm to ~1e-30; Poisson correction ~e-17765)
    for (int j = tid; j < TAPS; j += CBLK) {
        const float d = (float)(j - RAD);
        wlds[j] = expf(d * d * (-1.0f / 1800.0f)) * (float)(1.0 / 75.19884823893001);
    }

    // stage window [i0-176, i0-176+2400) with zero padding, swizzled
    const int st = i0 - HALO_L;
    for (int idx = tid; idx < WIN; idx += CBLK) {
        const int g = st + idx;
        const float val = (g >= 0 && g < SLEN) ? vrow[g] : 0.0f;
        lds[idx + (idx >> 3)] = val;
    }
    __syncthreads();

    // FIR: thread outputs i = i0 + 8*tid + t ; window idx x = 8*tid+16 + j + t
    float acc[TPO];
#pragma unroll
    for (int t = 0; t < TPO; ++t) acc[t] = 0.0f;

    float sreg[16];
    {
        const float* p0 = lds + 9 * (tid + 2);   // phi(8*(tid+2)+k) = 9*(tid+2)+k
        const float* p1 = lds + 9 * (tid + 3);
#pragma unroll
        for (int k = 0; k < 8; ++k) sreg[k] = p0[k];
#pragma unroll
        for (int k = 0; k < 8; ++k) sreg[8 + k] = p1[k];
    }

#pragma unroll 2
    for (int m = 0; m < 40; ++m) {
        const float4 w0 = *(const float4*)(wlds + 8 * m);       // uniform -> broadcast
        const float4 w1 = *(const float4*)(wlds + 8 * m + 4);
        const float wc[8] = {w0.x, w0.y, w0.z, w0.w, w1.x, w1.y, w1.z, w1.w};
#pragma unroll
        for (int c = 0; c < 8; ++c) {
#pragma unroll
            for (int t = 0; t < TPO; ++t) acc[t] += wc[c] * sreg[c + t];
        }
#pragma unroll
        for (int k = 0; k < 8; ++k) sreg[k] = sreg[k + 8];
        const float* pn = lds + 9 * (tid + m + 4);
#pragma unroll
        for (int k = 0; k < 8; ++k) sreg[8 + k] = pn[k];
    }
    {   // final tap j = 320: sreg[t] = win[8tid+16+320+t]
        const float wc = wlds[TAPS - 1];
#pragma unroll
        for (int t = 0; t < TPO; ++t) acc[t] += wc * sreg[t];
    }

    // block-edge v_s values (single-lane dots; hidden by other resident waves)
    float leftE = 0.0f, rightE = 0.0f;
    if (tid == 0) {          // v_s[i0-1]: win idx 15+j
        for (int j = 0; j < TAPS; ++j) {
            const int x = 15 + j;
            leftE += wlds[j] * lds[x + (x >> 3)];
        }
    }
    if (tid == CBLK - 1) {   // v_s[i0+2048]: win idx 2064+j
        for (int j = 0; j < TAPS; ++j) {
            const int x = 2064 + j;
            rightE += wlds[j] * lds[x + (x >> 3)];
        }
    }

    eL[tid] = acc[0];
    eR[tid] = acc[7];
    __syncthreads();
    const float eRp = (tid > 0)        ? eR[tid - 1] : leftE;
    const float eLn = (tid < CBLK - 1) ? eL[tid + 1] : rightE;

    // physics epilogue
    const float kk = wsp[row];
    const float aa = wsp[512 + row];
    const float ee = wsp[1024 + row];
    const float gg = wsp[1536 + row];
    const int uc = *use_cond;

    constexpr float DT = 1.6f / 7999.0f;
    constexpr float C1 = 1.0f / (2.0f * DT);
    constexpr float C2 = 1.0f / (DT * DT);

    const int i8 = i0 + 8 * tid;
    float dvt8[TPO], dv28[TPO], lg8[TPO];
#pragma unroll
    for (int t = 0; t < TPO; ++t) {
        const int i = i8 + t;
        const float vc = acc[t];
        float vm = (t == 0) ? eRp : acc[t - 1];
        float vp = (t == TPO - 1) ? eLn : acc[t + 1];
        if (i == 0) vm = 0.0f;
        if (i == SLEN - 1) vp = 0.0f;

        const float dv_t = (vp - vm) * C1;
        const float dv2  = (vp + vm - 2.0f * vc) * C2;

        float vn = (vc == 0.0f) ? 0.001f : vc;
        float inv_v = 1.0f / vn;
        if (inv_v != inv_v) inv_v = 0.0f;

        const float term_l1 = vc * kk * dv_t * (1.0f - 2.0f * vc + aa);
        const float term_l2 = inv_v * dv_t * dv_t;
        const float term_lt = 1000.0f * term_l1 + term_l2 - dv2;
        const float term_r1 = vc * (vc - gg * kk * 1000.0f * (1.0f - vc) * (vc - aa));
        const float term_rt = ee * (term_r1 + gg * dv_t);
        float dvo = term_lt - term_rt;
        if (uc) {
            if (vrow[i < SLEN ? i : 0] <= 0.0f) dvo = 0.0f;
        }
        dvt8[t] = dv_t;
        dv28[t] = dv2;
        lg8[t]  = logf(dvo * dvo + 1e-5f);
    }

    if (i8 < SLEN) {   // threads are entirely in-range or entirely OOB (8|8000)
        const long rs = (long)row * SLEN + i8;
        *(float4*)(out1 + rs)     = make_float4(dvt8[0], dvt8[1], dvt8[2], dvt8[3]);
        *(float4*)(out1 + rs + 4) = make_float4(dvt8[4], dvt8[5], dvt8[6], dvt8[7]);
        *(float4*)(out2 + rs)     = make_float4(dv28[0], dv28[1], dv28[2], dv28[3]);
        *(float4*)(out2 + rs + 4) = make_float4(dv28[4], dv28[5], dv28[6], dv28[7]);
        const float4 c16 = make_float4(1.6f, 1.6f, 1.6f, 1.6f);
        *(float4*)(out7 + rs)      = c16;
        *(float4*)(out7 + rs + 4)  = c16;
        *(float4*)(out10 + rs)     = c16;
        *(float4*)(out10 + rs + 4) = c16;

        const long rb = (long)row * (SLEN + 1) + i8;
        f4u a0 = {acc[0], acc[1], acc[2], acc[3]};
        f4u a1 = {acc[4], acc[5], acc[6], acc[7]};
        *(f4u*)(dvr + rb)     = a0;          // dv_r[i] = v_s[i]
        *(f4u*)(dvr + rb + 4) = a1;
        *(f4u*)(dvl + rb + 1) = a0;          // dv_l[i+1] = v_s[i]
        *(f4u*)(dvl + rb + 5) = a1;
        if (i8 == 0)        dvl[(long)row * (SLEN + 1)] = 0.0f;
        if (i8 == SLEN - 8) dvr[(long)row * (SLEN + 1) + SLEN] = 0.0f;

        const long r0 = (long)row * 7700;
#pragma unroll
        for (int t = 0; t < TPO; ++t) {
            const int i = i8 + t;
            if (i >= 100 && i < 950)        out0[r0 + (i - 100)] = lg8[t];
            else if (i >= 1050 && i < 7900) out0[r0 + (i - 200)] = lg8[t];
        }
    }
}

extern "C" void kernel_launch(void* const* d_in, const int* in_sizes, int n_in,
                              void* d_out, int out_size, void* d_ws, size_t ws_size,
                              hipStream_t stream)
{
    const float* v_out = (const float*)d_in[0];
    const float* b  = (const float*)d_in[1];
    const float* kw = (const float*)d_in[2];
    const float* kb = (const float*)d_in[3];
    const float* aw = (const float*)d_in[4];
    const float* ab = (const float*)d_in[5];
    const float* ew = (const float*)d_in[6];
    const float* eb = (const float*)d_in[7];
    const float* gw = (const float*)d_in[8];
    const float* gb = (const float*)d_in[9];
    const int* use_cond = (const int*)d_in[10];
    float* out = (float*)d_out;
    float* wsp = (float*)d_ws;   // 2048 floats: k,a,eps,gamma per row

    pc_params_kernel<<<NBATCH, 256, 0, stream>>>(
        b, kw, kb, aw, ab, ew, eb, gw, gb,
        out + O3, out + O4, out + O5, out + O6, wsp);

    pc_fused_kernel<<<dim3((SLEN + CHUNK - 1) / CHUNK, NBATCH), CBLK, 0, stream>>>(
        v_out, wsp, use_cond,
        out + O0, out + O1, out + O2, out + O7,
        out + O8, out + O9, out + O10);
}